// Round 1
// baseline (758.717 us; speedup 1.0000x reference)
//
#include <hip/hip_runtime.h>
#include <hip/hip_bf16.h>

// DiversityMemory: out[256,65536] = inputs[256,2048] @ features[65536,2048]^T
// Memory-bound GEMM-NT: features streamed from HBM once (BM=256 = full M),
// fp32 -> bf16 conversion fused into LDS staging, 16x16x32 bf16 MFMA.

typedef __bf16 bf16x8 __attribute__((ext_vector_type(8)));
typedef float  f32x4  __attribute__((ext_vector_type(4)));

constexpr int M = 256, K = 2048, N = 65536;
constexpr int BM = 256, BN = 128, BK = 32;
constexpr int THREADS = 512;   // 8 waves: 4 (m) x 2 (n), 64x64 per wave

__device__ inline void pack8(__hip_bfloat16* dst, float4 v) {
    __hip_bfloat162 lo = __float22bfloat162_rn(make_float2(v.x, v.y));
    __hip_bfloat162 hi = __float22bfloat162_rn(make_float2(v.z, v.w));
    union { __hip_bfloat162 h[2]; unsigned long long u; } p;
    p.h[0] = lo; p.h[1] = hi;
    *reinterpret_cast<unsigned long long*>(dst) = p.u;   // 8-B LDS store
}

__global__ __launch_bounds__(THREADS, 4)
void dm_gemm(const float* __restrict__ A,   // inputs   [256][2048]
             const float* __restrict__ F,   // features [65536][2048]
             float* __restrict__ C) {       // out      [256][65536]
    __shared__ __hip_bfloat16 As[BM * BK];  // 16 KB
    __shared__ __hip_bfloat16 Bs[BN * BK];  //  8 KB

    const int tid  = threadIdx.x;
    const int lane = tid & 63;
    const int w    = tid >> 6;        // 0..7
    const int wr   = w & 3;           // wave m-group: rows wr*64..+64
    const int wc   = w >> 2;          // wave n-group: cols wc*64..+64
    const int r15  = lane & 15;
    const int quad = lane >> 4;

    // ---- staging layout: thread covers (row = tid>>3 + j*64, k4 = (tid&7)*4)
    const int trow = tid >> 3;          // 0..63
    const int tk4  = (tid & 7) * 4;     // float offset within BK
    const float* Ag = A + trow * K + tk4;                                  // + j*64*K
    const float* Fg = F + (size_t)(blockIdx.x * BN + trow) * K + tk4;      // + j*64*K
    __hip_bfloat16* Asw = As + trow * BK + tk4;                            // + j*64*BK
    __hip_bfloat16* Bsw = Bs + trow * BK + tk4;

    f32x4 acc[4][4] = {};   // [mi][ni], 64 f32/lane

    for (int k0 = 0; k0 < K; k0 += BK) {
        // ---- global fp32 loads (coalesced float4, 128B per row-tile)
        float4 av0 = *reinterpret_cast<const float4*>(Ag + 0 * 64 * K + k0);
        float4 av1 = *reinterpret_cast<const float4*>(Ag + 1 * 64 * K + k0);
        float4 av2 = *reinterpret_cast<const float4*>(Ag + 2 * 64 * K + k0);
        float4 av3 = *reinterpret_cast<const float4*>(Ag + 3 * 64 * K + k0);
        float4 bv0 = *reinterpret_cast<const float4*>(Fg + (size_t)0 * 64 * K + k0);
        float4 bv1 = *reinterpret_cast<const float4*>(Fg + (size_t)1 * 64 * K + k0);

        // ---- convert + stage to LDS (wave writes 512B contiguous: conflict-free)
        pack8(Asw + 0 * 64 * BK, av0);
        pack8(Asw + 1 * 64 * BK, av1);
        pack8(Asw + 2 * 64 * BK, av2);
        pack8(Asw + 3 * 64 * BK, av3);
        pack8(Bsw + 0 * 64 * BK, bv0);
        pack8(Bsw + 1 * 64 * BK, bv1);

        __syncthreads();

        // ---- fragments: lane holds T[row = tile*16 + (lane&15)][k = quad*8..+8]
        bf16x8 af[4], bfr[4];
        #pragma unroll
        for (int mi = 0; mi < 4; ++mi)
            af[mi] = *reinterpret_cast<const bf16x8*>(
                As + (wr * 64 + mi * 16 + r15) * BK + quad * 8);
        #pragma unroll
        for (int ni = 0; ni < 4; ++ni)
            bfr[ni] = *reinterpret_cast<const bf16x8*>(
                Bs + (wc * 64 + ni * 16 + r15) * BK + quad * 8);

        #pragma unroll
        for (int mi = 0; mi < 4; ++mi)
            #pragma unroll
            for (int ni = 0; ni < 4; ++ni)
                acc[mi][ni] = __builtin_amdgcn_mfma_f32_16x16x32_bf16(
                    af[mi], bfr[ni], acc[mi][ni], 0, 0, 0);

        __syncthreads();
    }

    // ---- epilogue: C/D layout col = lane&15, row = quad*4 + e  [m89/m91]
    const int col0 = blockIdx.x * BN + wc * 64 + r15;
    #pragma unroll
    for (int mi = 0; mi < 4; ++mi) {
        const int row0 = wr * 64 + mi * 16 + quad * 4;
        #pragma unroll
        for (int ni = 0; ni < 4; ++ni) {
            #pragma unroll
            for (int e = 0; e < 4; ++e) {
                C[(size_t)(row0 + e) * N + col0 + ni * 16] = acc[mi][ni][e];
            }
        }
    }
}

extern "C" void kernel_launch(void* const* d_in, const int* in_sizes, int n_in,
                              void* d_out, int out_size, void* d_ws, size_t ws_size,
                              hipStream_t stream) {
    const float* inputs   = (const float*)d_in[0];
    // d_in[1] = inputs_ema (unused), d_in[2] = indexes (unused)
    const float* features = (const float*)d_in[3];
    float* out = (float*)d_out;

    dim3 grid(N / BN);       // 512 blocks
    dim3 block(THREADS);     // 512 threads
    hipLaunchKernelGGL(dm_gemm, grid, block, 0, stream, inputs, features, out);
}